// Round 4
// baseline (190.420 us; speedup 1.0000x reference)
//
#include <hip/hip_runtime.h>

#define TSEQ 2048
#define CDIM 1024
#define NH 16
#define HS 64
#define BATCH 4

typedef __attribute__((ext_vector_type(8))) short short8;
typedef __attribute__((ext_vector_type(4))) short s16x4;
typedef __attribute__((ext_vector_type(4))) float f32x4;

__device__ __forceinline__ short f2bf(float f) {
    unsigned u = __builtin_bit_cast(unsigned, f);
    unsigned r = (u + 0x7fffu + ((u >> 16) & 1u)) >> 16;
    return (short)r;
}

__device__ __forceinline__ void gload_lds16(const void* g, void* l) {
    __builtin_amdgcn_global_load_lds((const __attribute__((address_space(1))) void*)g,
                                     (__attribute__((address_space(3))) void*)l, 16, 0, 0);
}

#define FENCE() asm volatile("" ::: "memory")
#define BAR()  do { FENCE(); __builtin_amdgcn_s_barrier(); FENCE(); } while (0)

// ---------------- x -> bf16 ----------------
__global__ void cvt_x(const float* __restrict__ x, short* __restrict__ o, int n4) {
    int i = blockIdx.x * 256 + threadIdx.x;
    if (i >= n4) return;
    float4 v = ((const float4*)x)[i];
    s16x4 r;
    r[0] = f2bf(v.x); r[1] = f2bf(v.y); r[2] = f2bf(v.z); r[3] = f2bf(v.w);
    ((s16x4*)o)[i] = r;
}

// -------- weight transpose+convert: z=0..2 -> Wcat rows [Wq;Wk;Wv], z=3 -> Wpt --------
__global__ void wtrans(const float* __restrict__ Wk, const float* __restrict__ Wq,
                       const float* __restrict__ Wv, const float* __restrict__ Wp,
                       short* __restrict__ Wcat, short* __restrict__ Wpt) {
    const float* src; short* dst;
    if (blockIdx.z == 0)      { src = Wq; dst = Wcat; }
    else if (blockIdx.z == 1) { src = Wk; dst = Wcat + 1048576; }
    else if (blockIdx.z == 2) { src = Wv; dst = Wcat + 2097152; }
    else                      { src = Wp; dst = Wpt; }
    __shared__ float tl[64][65];
    int tx = threadIdx.x & 63, ty = threadIdx.x >> 6;
    int k0 = blockIdx.x * 64, n0 = blockIdx.y * 64;
#pragma unroll
    for (int i = 0; i < 16; ++i) {
        int r = i * 4 + ty;
        tl[r][tx] = src[(size_t)(k0 + r) * CDIM + n0 + tx];
    }
    __syncthreads();
#pragma unroll
    for (int i = 0; i < 16; ++i) {
        int r = i * 4 + ty;
        dst[(size_t)(n0 + r) * CDIM + k0 + tx] = f2bf(tl[tx][r]);
    }
}

// ---------------- bias concat (float) ----------------
__global__ void bias_pack(const float* __restrict__ bq, const float* __restrict__ bk,
                          const float* __restrict__ bv, float* __restrict__ bcat) {
    int i = blockIdx.x * 256 + threadIdx.x;
    if (i < 1024) bcat[i] = bq[i];
    else if (i < 2048) bcat[i] = bk[i - 1024];
    else if (i < 3072) bcat[i] = bv[i - 2048];
}

// ==== 256x256-tile 4-phase GEMM with counted-vmcnt pipeline (T3+T4+T5+T1) ====
// C[M,N] = (A[M,1024] @ Bt[N,1024]^T + bias) * alpha(col).  8 waves = 2M x 4N,
// wave tile 128x64.  K-tile BK=64; staged as 8 slices of 64 rows (1 load/thread).
// Stage schedule (iter tau, p=tau&1, q=p^1):
//   Ph0: A1,A3(tau+1)->q   [dead since (tau-1).Ph2]
//   Ph1: A0,A2(tau+2)->p   [dead after tau.Ph0]     gate vmcnt(10) end-Ph1
//   Ph2: B0,B1(tau+2)->p   [B dead after tau.Ph1]
//   Ph3: B2,B3(tau+2)->p                             gate vmcnt(8)  end-Ph3
// Gate proofs: Ph2 needs A1,A3(tau) issued 4 phases prior; outstanding newer = 10.
//              next Ph0 needs A0,A2,B0-3(tau+1); outstanding newer = 8.
template <bool OUT_BF16>
__global__ __launch_bounds__(512, 2) void gemm256(const short* __restrict__ A,
                                                  const short* __restrict__ Bt,
                                                  const float* __restrict__ bias,
                                                  float alphaQ, int qcols,
                                                  void* __restrict__ Cout, int ldc,
                                                  int ntN) {
    __shared__ short As[2][16384];
    __shared__ short Bs[2][16384];
    const int t = threadIdx.x, lane = t & 63, w = t >> 6;
    const int lr = lane & 15, lg = lane >> 4;
    const int wr = w >> 2, wc = w & 3;
    // XCD-chunked swizzle (grid % 8 == 0 always here)
    const int cpx = gridDim.x >> 3;
    const int swz = (blockIdx.x & 7) * cpx + (blockIdx.x >> 3);
    const int mbase = (swz / ntN) * 256, nbase = (swz % ntN) * 256;
    const float alpha = (nbase < qcols) ? alphaQ : 1.0f;
    const int srow = t >> 3;
    const int so8 = ((t & 7) ^ (srow & 7)) * 8;      // pre-swizzled source chunk
    const int c0 = (lg ^ (lr & 7)) * 8;              // ds_read chunk, ks=0
    const int c1 = ((4 + lg) ^ (lr & 7)) * 8;        // ks=1
    const int NT = 16;  // K = 1024

#define STAGE_A(buf, s, tc) gload_lds16(A + (size_t)(mbase + (s) * 64 + srow) * 1024 + (tc) * 64 + so8, \
                                        &As[buf][(s) * 4096 + t * 8])
#define STAGE_B(buf, s, tc) gload_lds16(Bt + (size_t)(nbase + (s) * 64 + srow) * 1024 + (tc) * 64 + so8, \
                                        &Bs[buf][(s) * 4096 + t * 8])

    f32x4 acc[8][4] = {};
    short8 aL[2][4], aH[2][4], bA[2][2], bB[2][2];

    // ---- prologue: tile0 all 8 slices (buf0); tile1 A0,A2,B0..B3 (buf1) ----
    STAGE_A(0, 0, 0); STAGE_A(0, 1, 0); STAGE_A(0, 2, 0); STAGE_A(0, 3, 0);
    STAGE_B(0, 0, 0); STAGE_B(0, 1, 0); STAGE_B(0, 2, 0); STAGE_B(0, 3, 0);
    STAGE_A(1, 0, 1); STAGE_A(1, 2, 1);
    STAGE_B(1, 0, 1); STAGE_B(1, 1, 1); STAGE_B(1, 2, 1); STAGE_B(1, 3, 1);
    asm volatile("s_waitcnt vmcnt(6)" ::: "memory");
    __builtin_amdgcn_s_barrier();
    FENCE();

    for (int tau = 0; tau < NT; ++tau) {
        const int p = tau & 1, q = p ^ 1;
        const short* Ap = As[p];
        const short* Bp = Bs[p];
        const int t1 = (tau + 1 < NT) ? tau + 1 : NT - 1;
        const int t2 = (tau + 2 < NT) ? tau + 2 : NT - 1;
        // ---------- Ph0: read aLo + b01; stage A1,A3(t1)->q; MFMA miLo x ni01 ----------
#pragma unroll
        for (int mi = 0; mi < 4; ++mi) {
            const int ao = (wr * 128 + mi * 16 + lr) * 64;
            aL[0][mi] = *(const short8*)(Ap + ao + c0);
            aL[1][mi] = *(const short8*)(Ap + ao + c1);
        }
#pragma unroll
        for (int ni = 0; ni < 2; ++ni) {
            const int bo = (wc * 64 + ni * 16 + lr) * 64;
            bA[0][ni] = *(const short8*)(Bp + bo + c0);
            bA[1][ni] = *(const short8*)(Bp + bo + c1);
        }
        STAGE_A(q, 1, t1); STAGE_A(q, 3, t1);
        BAR();
        __builtin_amdgcn_s_setprio(1);
#pragma unroll
        for (int mi = 0; mi < 4; ++mi)
#pragma unroll
            for (int ni = 0; ni < 2; ++ni)
#pragma unroll
                for (int ks = 0; ks < 2; ++ks)
                    acc[mi][ni] = __builtin_amdgcn_mfma_f32_16x16x32_bf16(
                        aL[ks][mi], bA[ks][ni], acc[mi][ni], 0, 0, 0);
        __builtin_amdgcn_s_setprio(0);
        BAR();
        // ---------- Ph1: read b23; stage A0,A2(t2)->p; MFMA miLo x ni23; gate(10) ----------
#pragma unroll
        for (int ni = 0; ni < 2; ++ni) {
            const int bo = (wc * 64 + (ni + 2) * 16 + lr) * 64;
            bB[0][ni] = *(const short8*)(Bp + bo + c0);
            bB[1][ni] = *(const short8*)(Bp + bo + c1);
        }
        STAGE_A(p, 0, t2); STAGE_A(p, 2, t2);
        BAR();
        __builtin_amdgcn_s_setprio(1);
#pragma unroll
        for (int mi = 0; mi < 4; ++mi)
#pragma unroll
            for (int ni = 0; ni < 2; ++ni)
#pragma unroll
                for (int ks = 0; ks < 2; ++ks)
                    acc[mi][ni + 2] = __builtin_amdgcn_mfma_f32_16x16x32_bf16(
                        aL[ks][mi], bB[ks][ni], acc[mi][ni + 2], 0, 0, 0);
        __builtin_amdgcn_s_setprio(0);
        asm volatile("s_waitcnt vmcnt(10)" ::: "memory");
        __builtin_amdgcn_s_barrier();
        FENCE();
        // ---------- Ph2: read aHi; stage B0,B1(t2)->p; MFMA miHi x ni23 ----------
#pragma unroll
        for (int mi = 0; mi < 4; ++mi) {
            const int ao = (wr * 128 + (mi + 4) * 16 + lr) * 64;
            aH[0][mi] = *(const short8*)(Ap + ao + c0);
            aH[1][mi] = *(const short8*)(Ap + ao + c1);
        }
        STAGE_B(p, 0, t2); STAGE_B(p, 1, t2);
        BAR();
        __builtin_amdgcn_s_setprio(1);
#pragma unroll
        for (int mi = 0; mi < 4; ++mi)
#pragma unroll
            for (int ni = 0; ni < 2; ++ni)
#pragma unroll
                for (int ks = 0; ks < 2; ++ks)
                    acc[mi + 4][ni + 2] = __builtin_amdgcn_mfma_f32_16x16x32_bf16(
                        aH[ks][mi], bB[ks][ni], acc[mi + 4][ni + 2], 0, 0, 0);
        __builtin_amdgcn_s_setprio(0);
        BAR();
        // ---------- Ph3: stage B2,B3(t2)->p; MFMA miHi x ni01; gate(8) ----------
        STAGE_B(p, 2, t2); STAGE_B(p, 3, t2);
        __builtin_amdgcn_s_setprio(1);
#pragma unroll
        for (int mi = 0; mi < 4; ++mi)
#pragma unroll
            for (int ni = 0; ni < 2; ++ni)
#pragma unroll
                for (int ks = 0; ks < 2; ++ks)
                    acc[mi + 4][ni] = __builtin_amdgcn_mfma_f32_16x16x32_bf16(
                        aH[ks][mi], bA[ks][ni], acc[mi + 4][ni], 0, 0, 0);
        __builtin_amdgcn_s_setprio(0);
        asm volatile("s_waitcnt vmcnt(8)" ::: "memory");
        __builtin_amdgcn_s_barrier();
        FENCE();
    }
#undef STAGE_A
#undef STAGE_B
    // ---------- epilogue ----------
#pragma unroll
    for (int mi = 0; mi < 8; ++mi) {
#pragma unroll
        for (int ni = 0; ni < 4; ++ni) {
            const int col = nbase + wc * 64 + ni * 16 + lr;
            const float bv = bias[col];
#pragma unroll
            for (int ii = 0; ii < 4; ++ii) {
                const int row = mbase + wr * 128 + mi * 16 + lg * 4 + ii;
                const float v = (acc[mi][ni][ii] + bv) * alpha;
                if (OUT_BF16)
                    ((short*)Cout)[(size_t)row * ldc + col] = f2bf(v);
                else
                    ((float*)Cout)[(size_t)row * ldc + col] = v;
            }
        }
    }
}

// ---------------- V transpose: QKV V-section [b*T,h*64+d] -> Vt[bh][d][T] ----------------
__global__ void vtrans(const short* __restrict__ QKV, short* __restrict__ Vt) {
    __shared__ short tl[64][68];
    const int t = threadIdx.x;
    const int tx = t & 63, ty = t >> 6;
    const int t0 = blockIdx.x * 64, bh = blockIdx.y;
    const int b = bh >> 4, h = bh & 15;
#pragma unroll
    for (int i = 0; i < 16; ++i) {
        int row = i * 4 + ty;
        tl[row][tx] = QKV[(size_t)(b * TSEQ + t0 + row) * 3072 + 2048 + h * HS + tx];
    }
    __syncthreads();
#pragma unroll
    for (int i = 0; i < 16; ++i) {
        int d = i * 4 + ty;
        Vt[(size_t)(bh * 64 + d) * TSEQ + t0 + tx] = tl[tx][d];
    }
}

// ---------------- causal flash attention (fixed-shift softmax) ----------------
__global__ __launch_bounds__(512, 4) void attn(const short* __restrict__ QKV,
                                               const short* __restrict__ Vt,
                                               short* __restrict__ Y) {
    __shared__ short Kl[2][64 * 64];
    __shared__ short Vl[2][64 * 64];
    __shared__ short Pl[8][16 * 64];
    const int t = threadIdx.x, lane = t & 63, w = t >> 6;
    const int lr = lane & 15, lg = lane >> 4;
    const int bh = blockIdx.x, b = bh >> 4, h = bh & 15;
    const int qt = 15 - blockIdx.y;  // heavy blocks first (LPT)
    const int q0w = qt * 128 + w * 16;
    const size_t rowbase = (size_t)b * TSEQ;
    const int niter = 2 * qt + 2;
    const float SHIFT2 = 17.31234049f;  // 12 * log2(e)

    short8 qf[2];
#pragma unroll
    for (int ks = 0; ks < 2; ++ks)
        qf[ks] = *(const short8*)(QKV + (rowbase + q0w + lr) * 3072 + h * HS + ks * 32 + lg * 8);
    float l_i[4] = {0.f, 0.f, 0.f, 0.f};
    f32x4 o[4] = {};

    const int sr = t >> 3, sc = t & 7, scl = sc ^ (sr & 7);
    const short* Kg = QKV + 1024 + h * HS;  // K section
    gload_lds16(Kg + (rowbase + sr) * 3072 + scl * 8, &Kl[0][t * 8]);
    gload_lds16(Vt + (size_t)(bh * 64 + sr) * TSEQ + scl * 8, &Vl[0][t * 8]);
    __syncthreads();
    int buf = 0;
    for (int jt = 0; jt < niter; ++jt) {
        const int j0 = jt * 64;
        if (jt + 1 < niter) {
            const int j0n = j0 + 64;
            gload_lds16(Kg + (rowbase + j0n + sr) * 3072 + scl * 8, &Kl[buf ^ 1][t * 8]);
            gload_lds16(Vt + (size_t)(bh * 64 + sr) * TSEQ + j0n + scl * 8, &Vl[buf ^ 1][t * 8]);
        }
        if (j0 <= q0w + 15) {
            f32x4 s[4];
            __builtin_amdgcn_s_setprio(1);
#pragma unroll
            for (int nt = 0; nt < 4; ++nt) {
                s[nt] = f32x4{0.f, 0.f, 0.f, 0.f};
#pragma unroll
                for (int ks = 0; ks < 2; ++ks) {
                    short8 kf = *(const short8*)(&Kl[buf][(nt * 16 + lr) * 64 +
                                                          (((ks * 4 + lg) ^ (lr & 7)) * 8)]);
                    s[nt] = __builtin_amdgcn_mfma_f32_16x16x32_bf16(qf[ks], kf, s[nt], 0, 0, 0);
                }
            }
            __builtin_amdgcn_s_setprio(0);
            if (j0 + 63 > q0w) {  // diagonal: causal mask
#pragma unroll
                for (int nt = 0; nt < 4; ++nt)
#pragma unroll
                    for (int i = 0; i < 4; ++i) {
                        int kv = j0 + nt * 16 + lr;
                        int q = q0w + lg * 4 + i;
                        if (kv > q) s[nt][i] = -__builtin_inff();
                    }
            }
#pragma unroll
            for (int i = 0; i < 4; ++i) {
                const int ql = lg * 4 + i;
                float pt[4];
#pragma unroll
                for (int nt = 0; nt < 4; ++nt) {
                    float p = __builtin_amdgcn_exp2f(s[nt][i] - SHIFT2);
                    unsigned u = __builtin_bit_cast(unsigned, p);
                    int chv = ((nt * 2 + (lr >> 3)) ^ (ql & 7));
                    Pl[w][ql * 64 + chv * 8 + (lr & 7)] = (short)(u >> 16);  // trunc bf16
                    pt[nt] = __builtin_bit_cast(float, u & 0xffff0000u);     // same value as stored
                }
                l_i[i] += (pt[0] + pt[1]) + (pt[2] + pt[3]);
            }
            short8 pf[2];
#pragma unroll
            for (int ks = 0; ks < 2; ++ks)
                pf[ks] = *(const short8*)(&Pl[w][lr * 64 + (((ks * 4 + lg) ^ (lr & 7)) * 8)]);
            __builtin_amdgcn_s_setprio(1);
#pragma unroll
            for (int nd = 0; nd < 4; ++nd)
#pragma unroll
                for (int ks = 0; ks < 2; ++ks) {
                    short8 vf = *(const short8*)(&Vl[buf][(nd * 16 + lr) * 64 +
                                                          (((ks * 4 + lg) ^ (lr & 7)) * 8)]);
                    o[nd] = __builtin_amdgcn_mfma_f32_16x16x32_bf16(pf[ks], vf, o[nd], 0, 0, 0);
                }
            __builtin_amdgcn_s_setprio(0);
        }
        __syncthreads();
        buf ^= 1;
    }
#pragma unroll
    for (int i = 0; i < 4; ++i) {
        float l = l_i[i];
        l += __shfl_xor(l, 1);
        l += __shfl_xor(l, 2);
        l += __shfl_xor(l, 4);
        l += __shfl_xor(l, 8);
        float inv = 1.0f / l;
        int q = q0w + lg * 4 + i;
#pragma unroll
        for (int nd = 0; nd < 4; ++nd)
            Y[(rowbase + q) * 1024 + h * HS + nd * 16 + lr] = f2bf(o[nd][i] * inv);
    }
}

extern "C" void kernel_launch(void* const* d_in, const int* in_sizes, int n_in,
                              void* d_out, int out_size, void* d_ws, size_t ws_size,
                              hipStream_t stream) {
    const float* x  = (const float*)d_in[0];
    const float* Wk = (const float*)d_in[1];
    const float* bk = (const float*)d_in[2];
    const float* Wq = (const float*)d_in[3];
    const float* bq = (const float*)d_in[4];
    const float* Wv = (const float*)d_in[5];
    const float* bv = (const float*)d_in[6];
    const float* Wp = (const float*)d_in[7];
    const float* bp = (const float*)d_in[8];
    float* out = (float*)d_out;
    char* ws = (char*)d_ws;
    const size_t MB = 1024 * 1024;
    short* xb   = (short*)(ws);            // 16 MB (reused as Y after QKV GEMM)
    short* Wcat = (short*)(ws + 16 * MB);  // 6 MB: [Wq^T; Wk^T; Wv^T]
    short* Wpt  = (short*)(ws + 22 * MB);  // 2 MB
    short* QKVb = (short*)(ws + 24 * MB);  // 48 MB: [8192][3072]
    short* Yb   = xb;
    // scratch inside d_out (overwritten by final GEMM at the end):
    short* VtT  = (short*)d_out;                      // 16 MB: [64][64][2048]
    float* bcat = (float*)((char*)d_out + 16 * MB);   // 12 KB

    // Q prescale folds 1/sqrt(64) AND log2(e) (scores in log2 units for exp2 softmax)
    const float alphaQ = 0.125f * 1.44269504088896f;

    cvt_x<<<8192, 256, 0, stream>>>(x, xb, 2097152);
    wtrans<<<dim3(16, 16, 4), 256, 0, stream>>>(Wk, Wq, Wv, Wp, Wcat, Wpt);
    bias_pack<<<12, 256, 0, stream>>>(bq, bk, bv, bcat);
    gemm256<true><<<384, 512, 0, stream>>>(xb, Wcat, bcat, alphaQ, 1024, QKVb, 3072, 12);
    vtrans<<<dim3(32, 64), 256, 0, stream>>>(QKVb, VtT);
    attn<<<dim3(64, 16), 512, 0, stream>>>(QKVb, VtT, Yb);
    gemm256<false><<<128, 512, 0, stream>>>(Yb, Wpt, bp, 1.0f, 0, out, 1024, 4);
}